// Round 1
// baseline (581.274 us; speedup 1.0000x reference)
//
#include <hip/hip_runtime.h>
#include <hip/hip_bf16.h>
#include <cstdint>

typedef __hip_bfloat16 bf16;
typedef __attribute__((ext_vector_type(4))) float f32x4;
typedef __attribute__((ext_vector_type(8))) __bf16 bf16x8;

#define SCALE 0.17677669529663687f

// ---- workspace offsets (bytes) ----
// wtq 576x192 bf16, wtp 192x192, wt1 768x192, wt2 192x768, rmap 100352 int
// A: bf16 [100352][192] (win, later attn-out, later ln2-out)
// B: bf16 [100352][576] qkv, later [100352][768] hidden
// C: f32  [100352][192] h (residual mid)
#define OFF_WTQ   0
#define OFF_WTP   221184
#define OFF_WT1   294912
#define OFF_WT2   589824
#define OFF_RMAP  884736
#define OFF_A     1286144
#define OFF_B     39821312
#define OFF_C     193961984

__global__ __launch_bounds__(256) void prep_k(
    const float* __restrict__ qkv_w, const float* __restrict__ proj_w,
    const float* __restrict__ w1, const float* __restrict__ w2,
    bf16* __restrict__ wtq, bf16* __restrict__ wtp,
    bf16* __restrict__ wt1, bf16* __restrict__ wt2, int* __restrict__ rmap)
{
  int i = blockIdx.x * 256 + threadIdx.x;
  if (i < 110592) {                       // qkv_w (192,576) -> wtq[n][k]
    int n = i / 192, k = i - n * 192;
    wtq[i] = __float2bfloat16(qkv_w[k * 576 + n]);
  } else if (i < 147456) {                // proj_w (192,192)
    int j = i - 110592; int n = j / 192, k = j - n * 192;
    wtp[j] = __float2bfloat16(proj_w[k * 192 + n]);
  } else if (i < 294912) {                // w1 (192,768) -> wt1[768][192]
    int j = i - 147456; int n = j / 192, k = j - n * 192;
    wt1[j] = __float2bfloat16(w1[k * 768 + n]);
  } else if (i < 442368) {                // w2 (768,192) -> wt2[192][768]
    int j = i - 294912; int n = j / 768, k = j - n * 768;
    wt2[j] = __float2bfloat16(w2[k * 192 + n]);
  } else if (i < 542720) {                // rowmap: window row -> natural row
    int m = i - 442368;
    int win = m / 49, nn = m - win * 49;
    int b = win >> 6, iw = win & 63;
    int wh = iw >> 3, ww = iw & 7;
    int ty = nn / 7, tx = nn - ty * 7;
    int rr = wh * 7 + ty + 3; if (rr >= 56) rr -= 56;   // roll(-3) gather == roll(+3) scatter
    int cc = ww * 7 + tx + 3; if (cc >= 56) cc -= 56;
    rmap[m] = b * 3136 + rr * 56 + cc;
  }
}

// LayerNorm over 192, one wave per row, optional gather permutation, bf16 out
template<bool MAP>
__global__ __launch_bounds__(256) void ln_k(
    const float* __restrict__ x, const float* __restrict__ g,
    const float* __restrict__ b, const int* __restrict__ rmap,
    bf16* __restrict__ out)
{
  int wv = threadIdx.x >> 6, lane = threadIdx.x & 63;
  long m = (long)blockIdx.x * 4 + wv;
  long src = MAP ? (long)rmap[m] : m;
  const float* row = x + src * 192;
  float v0 = row[lane], v1 = row[lane + 64], v2 = row[lane + 128];
  float s = v0 + v1 + v2;
  #pragma unroll
  for (int d = 1; d < 64; d <<= 1) s += __shfl_xor(s, d, 64);
  float mu = s * (1.0f / 192.0f);
  float d0 = v0 - mu, d1 = v1 - mu, d2 = v2 - mu;
  float q = d0 * d0 + d1 * d1 + d2 * d2;
  #pragma unroll
  for (int d = 1; d < 64; d <<= 1) q += __shfl_xor(q, d, 64);
  float inv = 1.0f / sqrtf(q * (1.0f / 192.0f) + 1e-5f);
  bf16* o = out + m * 192;
  o[lane]       = __float2bfloat16(d0 * inv * g[lane]       + b[lane]);
  o[lane + 64]  = __float2bfloat16(d1 * inv * g[lane + 64]  + b[lane + 64]);
  o[lane + 128] = __float2bfloat16(d2 * inv * g[lane + 128] + b[lane + 128]);
}

// GEMM: C[M][ND] = A[M][KD] @ Wt^T + bias, fused epilogue.
// MODE 0: ->bf16 qkv   1: +x residual scatter ->f32 h
//      2: gelu ->bf16  3: +h ->f32 d_out
// Block 128x64 tile, 4 waves (2x2), BK=64, A via global_load_lds (swizzled).
template<int MODE, int KD>
__global__ __launch_bounds__(256) void gemm_k(
    const bf16* __restrict__ A, const bf16* __restrict__ Bt,
    const float* __restrict__ bias, const float* __restrict__ extra,
    const int* __restrict__ rmap, void* __restrict__ outp)
{
  __shared__ bf16 As[128 * 64];
  const int tid = threadIdx.x;
  const int lane = tid & 63;
  const int w = tid >> 6;
  const int wm = w >> 1, wn = w & 1;
  const long m0 = (long)blockIdx.y * 128;
  const int n0 = blockIdx.x * 64;
  const int r = lane & 15, kb = lane >> 4;

  f32x4 acc[4][2];
  #pragma unroll
  for (int a = 0; a < 4; ++a)
    #pragma unroll
    for (int bb = 0; bb < 2; ++bb) acc[a][bb] = (f32x4){0.f, 0.f, 0.f, 0.f};

  for (int k0 = 0; k0 < KD; k0 += 64) {
    #pragma unroll
    for (int it = 0; it < 4; ++it) {
      int li = tid + it * 256;          // 16B unit index 0..1023
      int m = li >> 3;
      int sl = (li & 7) ^ (m & 7);      // inverse-swizzled source slot
      const bf16* src = A + (m0 + m) * KD + k0 + sl * 8;
      bf16* dst = As + (size_t)(w * 64 + it * 256) * 8;   // wave-uniform base
      __builtin_amdgcn_global_load_lds(
          (const __attribute__((address_space(1))) unsigned int*)src,
          (__attribute__((address_space(3))) unsigned int*)dst, 16, 0, 0);
    }
    __syncthreads();

    bf16x8 af[2][4], bfr[2][2];
    #pragma unroll
    for (int h2 = 0; h2 < 2; ++h2) {
      #pragma unroll
      for (int mi = 0; mi < 4; ++mi) {
        int m = wm * 64 + mi * 16 + r;
        int slot = (h2 * 4 + kb) ^ (r & 7);   // swizzled read
        af[h2][mi] = *(const bf16x8*)(As + m * 64 + slot * 8);
      }
      #pragma unroll
      for (int ni = 0; ni < 2; ++ni) {
        int n = n0 + wn * 32 + ni * 16 + r;
        bfr[h2][ni] = *(const bf16x8*)(Bt + (long)n * KD + k0 + h2 * 32 + kb * 8);
      }
    }
    #pragma unroll
    for (int h2 = 0; h2 < 2; ++h2)
      #pragma unroll
      for (int mi = 0; mi < 4; ++mi)
        #pragma unroll
        for (int ni = 0; ni < 2; ++ni)
          acc[mi][ni] = __builtin_amdgcn_mfma_f32_16x16x32_bf16(
              af[h2][mi], bfr[h2][ni], acc[mi][ni], 0, 0, 0);
    __syncthreads();
  }

  #pragma unroll
  for (int mi = 0; mi < 4; ++mi) {
    #pragma unroll
    for (int ni = 0; ni < 2; ++ni) {
      int col = n0 + wn * 32 + ni * 16 + r;
      float bb = bias[col];
      #pragma unroll
      for (int rr = 0; rr < 4; ++rr) {
        long row = m0 + wm * 64 + mi * 16 + kb * 4 + rr;
        float c = acc[mi][ni][rr] + bb;
        if constexpr (MODE == 0) {
          ((bf16*)outp)[row * 576 + col] = __float2bfloat16(c);
        } else if constexpr (MODE == 1) {
          long gr = rmap[row];
          ((float*)outp)[gr * 192 + col] = extra[gr * 192 + col] + c;
        } else if constexpr (MODE == 2) {
          float ge = 0.5f * c * (1.0f + erff(c * 0.70710678118654752f));
          ((bf16*)outp)[row * 768 + col] = __float2bfloat16(ge);
        } else {
          ((float*)outp)[row * 192 + col] = extra[row * 192 + col] + c;
        }
      }
    }
  }
}

// Attention: one wave per (window, head). 49 tokens padded to 64.
__global__ __launch_bounds__(64) void attn_k(
    const bf16* __restrict__ qkv, const float* __restrict__ rpb,
    bf16* __restrict__ aout)
{
  __shared__ bf16 P[64 * 72];    // probs, padded stride
  __shared__ bf16 Vt[32 * 72];   // V transposed [d][j]
  int lane = threadIdx.x;
  int r = lane & 15, kb = lane >> 4;
  int head = blockIdx.x % 6;
  int win = blockIdx.x / 6;
  int iw = win & 63;
  int wh = iw >> 3, ww = iw & 7;
  const bf16* base = qkv + (long)win * (49 * 576);

  bf16x8 qf[4], kf[4];
  #pragma unroll
  for (int t = 0; t < 4; ++t) {
    int row = t * 16 + r;
    if (row < 49) {
      qf[t] = *(const bf16x8*)(base + row * 576 + head * 32 + kb * 8);
      kf[t] = *(const bf16x8*)(base + row * 576 + 192 + head * 32 + kb * 8);
    } else {
      qf[t] = (bf16x8){0, 0, 0, 0, 0, 0, 0, 0};
      kf[t] = (bf16x8){0, 0, 0, 0, 0, 0, 0, 0};
    }
  }
  f32x4 zero = {0.f, 0.f, 0.f, 0.f};
  f32x4 s[4][4];
  #pragma unroll
  for (int ti = 0; ti < 4; ++ti)
    #pragma unroll
    for (int tj = 0; tj < 4; ++tj)
      s[ti][tj] = __builtin_amdgcn_mfma_f32_16x16x32_bf16(qf[ti], kf[tj], zero, 0, 0, 0);

  { // stage V^T
    int j = lane;
    if (j < 49) {
      #pragma unroll
      for (int d0 = 0; d0 < 32; d0 += 8) {
        bf16x8 v8 = *(const bf16x8*)(base + j * 576 + 384 + head * 32 + d0);
        #pragma unroll
        for (int u = 0; u < 8; ++u) Vt[(d0 + u) * 72 + j] = *((const bf16*)&v8 + u);
      }
    } else {
      for (int d = 0; d < 32; ++d) Vt[d * 72 + j] = __float2bfloat16(0.0f);
    }
  }

  // softmax (rpb + shift mask computed inline)
  #pragma unroll
  for (int ti = 0; ti < 4; ++ti) {
    #pragma unroll
    for (int rr = 0; rr < 4; ++rr) {
      int i = ti * 16 + kb * 4 + rr;
      int ii = i < 49 ? i : 48;
      int yi = ii / 7, xi = ii - yi * 7;
      int ari = wh * 7 + yi, aci = ww * 7 + xi;
      int gi = (ari < 49 ? 0 : (ari < 53 ? 1 : 2)) * 3 + (aci < 49 ? 0 : (aci < 53 ? 1 : 2));
      float vals[4];
      #pragma unroll
      for (int tj = 0; tj < 4; ++tj) {
        int j = tj * 16 + r;
        int jj = j < 49 ? j : 48;
        int yj = jj / 7, xj = jj - yj * 7;
        float pb = rpb[((yi - yj + 6) * 13 + (xi - xj + 6)) * 6 + head];
        int arj = wh * 7 + yj, acj = ww * 7 + xj;
        int gj = (arj < 49 ? 0 : (arj < 53 ? 1 : 2)) * 3 + (acj < 49 ? 0 : (acj < 53 ? 1 : 2));
        float v = s[ti][tj][rr] * SCALE + pb;
        if (gi != gj) v -= 100.0f;
        if (i >= 49 || j >= 49) v = -1e30f;
        vals[tj] = v;
      }
      float mx = fmaxf(fmaxf(vals[0], vals[1]), fmaxf(vals[2], vals[3]));
      #pragma unroll
      for (int d = 1; d < 16; d <<= 1) mx = fmaxf(mx, __shfl_xor(mx, d, 64));
      float e0 = __expf(vals[0] - mx), e1 = __expf(vals[1] - mx);
      float e2 = __expf(vals[2] - mx), e3 = __expf(vals[3] - mx);
      float sum = e0 + e1 + e2 + e3;
      #pragma unroll
      for (int d = 1; d < 16; d <<= 1) sum += __shfl_xor(sum, d, 64);
      float inv = 1.0f / sum;
      P[i * 72 + 0  + r] = __float2bfloat16(e0 * inv);
      P[i * 72 + 16 + r] = __float2bfloat16(e1 * inv);
      P[i * 72 + 32 + r] = __float2bfloat16(e2 * inv);
      P[i * 72 + 48 + r] = __float2bfloat16(e3 * inv);
    }
  }
  __syncthreads();

  f32x4 o[4][2];
  #pragma unroll
  for (int ti = 0; ti < 4; ++ti)
    #pragma unroll
    for (int dt = 0; dt < 2; ++dt) o[ti][dt] = zero;
  #pragma unroll
  for (int kt = 0; kt < 2; ++kt) {
    bf16x8 pf[4], vf[2];
    #pragma unroll
    for (int ti = 0; ti < 4; ++ti)
      pf[ti] = *(const bf16x8*)(P + (ti * 16 + r) * 72 + kt * 32 + kb * 8);
    #pragma unroll
    for (int dt = 0; dt < 2; ++dt)
      vf[dt] = *(const bf16x8*)(Vt + (dt * 16 + r) * 72 + kt * 32 + kb * 8);
    #pragma unroll
    for (int ti = 0; ti < 4; ++ti)
      #pragma unroll
      for (int dt = 0; dt < 2; ++dt)
        o[ti][dt] = __builtin_amdgcn_mfma_f32_16x16x32_bf16(pf[ti], vf[dt], o[ti][dt], 0, 0, 0);
  }
  #pragma unroll
  for (int ti = 0; ti < 4; ++ti)
    #pragma unroll
    for (int dt = 0; dt < 2; ++dt)
      #pragma unroll
      for (int rr = 0; rr < 4; ++rr) {
        int i = ti * 16 + kb * 4 + rr;
        if (i < 49)
          aout[((long)win * 49 + i) * 192 + head * 32 + dt * 16 + r] =
              __float2bfloat16(o[ti][dt][rr]);
      }
}

extern "C" void kernel_launch(void* const* d_in, const int* in_sizes, int n_in,
                              void* d_out, int out_size, void* d_ws, size_t ws_size,
                              hipStream_t stream)
{
  const float* x      = (const float*)d_in[0];
  const float* qkv_w  = (const float*)d_in[1];
  const float* qkv_b  = (const float*)d_in[2];
  const float* proj_w = (const float*)d_in[3];
  const float* proj_b = (const float*)d_in[4];
  const float* rpb    = (const float*)d_in[5];
  const float* ln1_g  = (const float*)d_in[6];
  const float* ln1_b  = (const float*)d_in[7];
  const float* ln2_g  = (const float*)d_in[8];
  const float* ln2_b  = (const float*)d_in[9];
  const float* w1     = (const float*)d_in[10];
  const float* b1     = (const float*)d_in[11];
  const float* w2     = (const float*)d_in[12];
  const float* b2     = (const float*)d_in[13];
  // d_in[14]=H, d_in[15]=W fixed at 56 for this problem

  char* ws = (char*)d_ws;
  bf16* wtq = (bf16*)(ws + OFF_WTQ);
  bf16* wtp = (bf16*)(ws + OFF_WTP);
  bf16* wt1 = (bf16*)(ws + OFF_WT1);
  bf16* wt2 = (bf16*)(ws + OFF_WT2);
  int*  rmap = (int*)(ws + OFF_RMAP);
  bf16* Abuf = (bf16*)(ws + OFF_A);
  bf16* Bbuf = (bf16*)(ws + OFF_B);
  float* hbuf = (float*)(ws + OFF_C);

  prep_k<<<2120, 256, 0, stream>>>(qkv_w, proj_w, w1, w2, wtq, wtp, wt1, wt2, rmap);
  ln_k<true><<<25088, 256, 0, stream>>>(x, ln1_g, ln1_b, rmap, Abuf);
  gemm_k<0, 192><<<dim3(9, 784), 256, 0, stream>>>(Abuf, wtq, qkv_b, nullptr, nullptr, Bbuf);
  attn_k<<<12288, 64, 0, stream>>>(Bbuf, rpb, Abuf);
  gemm_k<1, 192><<<dim3(3, 784), 256, 0, stream>>>(Abuf, wtp, proj_b, x, rmap, hbuf);
  ln_k<false><<<25088, 256, 0, stream>>>(hbuf, ln2_g, ln2_b, nullptr, Abuf);
  gemm_k<2, 192><<<dim3(12, 784), 256, 0, stream>>>(Abuf, wt1, b1, nullptr, nullptr, Bbuf);
  gemm_k<3, 768><<<dim3(3, 784), 256, 0, stream>>>(Bbuf, wt2, b2, hbuf, nullptr, (float*)d_out);
}